// Round 1
// baseline (1517.583 us; speedup 1.0000x reference)
//
#include <hip/hip_runtime.h>
#include <hip/hip_bf16.h>
#include <math.h>

// ---------------------------------------------------------------------------
// Problem constants
// ---------------------------------------------------------------------------
#define BS   32
#define LQ   500
#define DIM  256
#define NHD  8
#define HD   32
#define FF   1024
#define SP   12
#define MTOT (BS*LQ)          // 16000 rows

// ---------------------------------------------------------------------------
// Generic fp32 tiled GEMM: C = act(A @ W + bias)
// A: M x K row-major, W: K x N row-major, C: M x N
// BM=128, BN=128, BK=16, 256 threads, 8x8 per thread.
// M must be a multiple of 128 and K a multiple of 16 (true for all our calls).
// N is guarded (handles N=288).
// ---------------------------------------------------------------------------
template<bool RELU, bool SIG>
__global__ __launch_bounds__(256)
void gemm_kernel(const float* __restrict__ A, const float* __restrict__ W,
                 const float* __restrict__ bias, float* __restrict__ C,
                 int M, int N, int K) {
  __shared__ __align__(16) float As[16][132];
  __shared__ __align__(16) float Bs[16][132];
  const int tid = threadIdx.x;
  const int tx = tid & 15, ty = tid >> 4;
  const int m0 = blockIdx.y * 128;
  const int n0 = blockIdx.x * 128;

  float acc[8][8];
#pragma unroll
  for (int i = 0; i < 8; ++i)
#pragma unroll
    for (int j = 0; j < 8; ++j) acc[i][j] = 0.f;

  const int nk = K >> 4;
  for (int kt = 0; kt < nk; ++kt) {
    const int k0 = kt << 4;
    // load A tile (128x16) -> As transposed [kk][m]
#pragma unroll
    for (int l = 0; l < 2; ++l) {
      int idx = tid + l * 256;          // 0..511
      int row = idx >> 2;               // 0..127
      int kk4 = (idx & 3) << 2;         // 0,4,8,12
      float4 av = *reinterpret_cast<const float4*>(
          &A[(size_t)(m0 + row) * K + k0 + kk4]);
      As[kk4 + 0][row] = av.x;
      As[kk4 + 1][row] = av.y;
      As[kk4 + 2][row] = av.z;
      As[kk4 + 3][row] = av.w;
    }
    // load B tile (16x128) -> Bs[kk][n]
#pragma unroll
    for (int l = 0; l < 2; ++l) {
      int idx = tid + l * 256;          // 0..511
      int kk = idx >> 5;                // 0..15
      int n4 = (idx & 31) << 2;         // 0..124
      int col = n0 + n4;
      float4 bv = make_float4(0.f, 0.f, 0.f, 0.f);
      if (col < N)
        bv = *reinterpret_cast<const float4*>(&W[(size_t)(k0 + kk) * N + col]);
      *reinterpret_cast<float4*>(&Bs[kk][n4]) = bv;
    }
    __syncthreads();
#pragma unroll
    for (int kk = 0; kk < 16; ++kk) {
      float a[8], b[8];
      *(float4*)&a[0] = *(const float4*)&As[kk][ty * 8 + 0];
      *(float4*)&a[4] = *(const float4*)&As[kk][ty * 8 + 4];
      *(float4*)&b[0] = *(const float4*)&Bs[kk][tx * 8 + 0];
      *(float4*)&b[4] = *(const float4*)&Bs[kk][tx * 8 + 4];
#pragma unroll
      for (int i = 0; i < 8; ++i)
#pragma unroll
        for (int j = 0; j < 8; ++j) acc[i][j] += a[i] * b[j];
    }
    __syncthreads();
  }

  // epilogue
  float bb[8];
#pragma unroll
  for (int j = 0; j < 8; ++j) {
    int col = n0 + tx * 8 + j;
    bb[j] = (col < N) ? bias[col] : 0.f;
  }
#pragma unroll
  for (int i = 0; i < 8; ++i) {
    int mrow = m0 + ty * 8 + i;
#pragma unroll
    for (int j4 = 0; j4 < 2; ++j4) {
      int col = n0 + tx * 8 + j4 * 4;
      if (col < N) {
        float4 o;
        float v0 = acc[i][j4 * 4 + 0] + bb[j4 * 4 + 0];
        float v1 = acc[i][j4 * 4 + 1] + bb[j4 * 4 + 1];
        float v2 = acc[i][j4 * 4 + 2] + bb[j4 * 4 + 2];
        float v3 = acc[i][j4 * 4 + 3] + bb[j4 * 4 + 3];
        if (RELU) {
          v0 = fmaxf(v0, 0.f); v1 = fmaxf(v1, 0.f);
          v2 = fmaxf(v2, 0.f); v3 = fmaxf(v3, 0.f);
        }
        if (SIG) {
          v0 = 1.f / (1.f + __expf(-v0));
          v1 = 1.f / (1.f + __expf(-v1));
          v2 = 1.f / (1.f + __expf(-v2));
          v3 = 1.f / (1.f + __expf(-v3));
        }
        o.x = v0; o.y = v1; o.z = v2; o.w = v3;
        *reinterpret_cast<float4*>(&C[(size_t)mrow * N + col]) = o;
      }
    }
  }
}

// ---------------------------------------------------------------------------
// Flash self-attention. grid (256 bh, 2 q-tiles), block 256.
// K/V for one (b,h) staged in LDS in two 250-row tiles; online softmax.
// qkproj: [M][512] (cols 0..255 = Q head-major, 256..511 = K)
// v:      [M][256]
// sa out: [M][256]
// ---------------------------------------------------------------------------
__global__ __launch_bounds__(256)
void attn_kernel(const float* __restrict__ qkproj, const float* __restrict__ v,
                 float* __restrict__ sa) {
  __shared__ __align__(16) float Ks[250 * 32];
  __shared__ __align__(16) float Vs[250 * 32];
  const int tid = threadIdx.x;
  const int bh = blockIdx.x;
  const int b = bh >> 3, h = bh & 7;
  const int qi = blockIdx.y * 250 + tid;
  const bool active = tid < 250;

  float q[32], acc[32];
  float mrun = -1e30f, l = 0.f;
  if (active) {
    const float* qp = &qkproj[(size_t)(b * 500 + qi) * 512 + h * 32];
#pragma unroll
    for (int d4 = 0; d4 < 8; ++d4)
      *(float4*)&q[d4 * 4] = *(const float4*)&qp[d4 * 4];
#pragma unroll
    for (int d = 0; d < 32; ++d) acc[d] = 0.f;
  }

  for (int t0 = 0; t0 < 500; t0 += 250) {
    __syncthreads();
    for (int idx = tid; idx < 2000; idx += 256) {
      int r = idx >> 3, d4 = idx & 7;
      size_t row = (size_t)(b * 500 + t0 + r);
      ((float4*)Ks)[idx] =
          *(const float4*)&qkproj[row * 512 + 256 + h * 32 + d4 * 4];
      ((float4*)Vs)[idx] = *(const float4*)&v[row * 256 + h * 32 + d4 * 4];
    }
    __syncthreads();
    if (active) {
      for (int r = 0; r < 250; ++r) {
        const float4* kr = (const float4*)&Ks[r * 32];
        float s0 = 0.f, s1 = 0.f, s2 = 0.f, s3 = 0.f;
#pragma unroll
        for (int d4 = 0; d4 < 8; ++d4) {
          float4 kv = kr[d4];
          s0 += q[d4 * 4 + 0] * kv.x;
          s1 += q[d4 * 4 + 1] * kv.y;
          s2 += q[d4 * 4 + 2] * kv.z;
          s3 += q[d4 * 4 + 3] * kv.w;
        }
        float s = ((s0 + s1) + (s2 + s3)) * 0.17677669529663687f;
        if (s > mrun) {
          float corr = __expf(mrun - s);
          l *= corr;
#pragma unroll
          for (int d = 0; d < 32; ++d) acc[d] *= corr;
          mrun = s;
        }
        float p = __expf(s - mrun);
        l += p;
        const float4* vr = (const float4*)&Vs[r * 32];
#pragma unroll
        for (int d4 = 0; d4 < 8; ++d4) {
          float4 vv = vr[d4];
          acc[d4 * 4 + 0] += p * vv.x;
          acc[d4 * 4 + 1] += p * vv.y;
          acc[d4 * 4 + 2] += p * vv.z;
          acc[d4 * 4 + 3] += p * vv.w;
        }
      }
    }
  }
  if (active) {
    float inv = 1.f / l;
    float* op = &sa[(size_t)(b * 500 + qi) * 256 + h * 32];
#pragma unroll
    for (int d4 = 0; d4 < 8; ++d4) {
      float4 o;
      o.x = acc[d4 * 4 + 0] * inv;
      o.y = acc[d4 * 4 + 1] * inv;
      o.z = acc[d4 * 4 + 2] * inv;
      o.w = acc[d4 * 4 + 3] * inv;
      *(float4*)&op[d4 * 4] = o;
    }
  }
}

// ---------------------------------------------------------------------------
// CHW -> HWC transpose of one value level. grid (256, ceil(HW/64)), block 256.
// ---------------------------------------------------------------------------
__global__ __launch_bounds__(256)
void transpose_kernel(const float* __restrict__ in, float* __restrict__ out,
                      int HW) {
  __shared__ float ts[32][65];
  const int bn = blockIdx.x;
  const int p0 = blockIdx.y * 64;
  const int tid = threadIdx.x;
  {
    const int lane = tid & 63, cg = tid >> 6;
#pragma unroll
    for (int i = 0; i < 8; ++i) {
      int cc = cg * 8 + i;
      int p = p0 + lane;
      if (p < HW) ts[cc][lane] = in[(size_t)bn * 32 * HW + (size_t)cc * HW + p];
    }
  }
  __syncthreads();
  {
    const int cc = tid & 31, pg = tid >> 5;
#pragma unroll
    for (int i = 0; i < 8; ++i) {
      int p = pg * 8 + i;
      int pos = p0 + p;
      if (pos < HW)
        out[(size_t)bn * HW * 32 + (size_t)pos * 32 + cc] = ts[cc][p];
    }
  }
}

// ---------------------------------------------------------------------------
// Deformable sampler. grid 16000 (one per (b,q)), block 256 = 8 heads x 32 ch.
// Reads offaw [M][288] (0..191 offsets head-major, 192..287 attn logits),
// ref_pts [M][4], value levels (HWC if fast path, CHW fallback).
// Writes t2d into cat[:, 256:512].
// ---------------------------------------------------------------------------
template<bool HWC>
__global__ __launch_bounds__(256)
void sampler_kernel(const float* __restrict__ offaw,
                    const float* __restrict__ refp,
                    const float* __restrict__ v0,
                    const float* __restrict__ v1,
                    const float* __restrict__ v2,
                    float* __restrict__ catbuf) {
  const int m = blockIdx.x;
  const int tid = threadIdx.x;
  const int h = tid >> 5, c = tid & 31;
  const int b = m / 500;
  const int bn = b * 8 + h;

  const float rx = refp[m * 4 + 0], ry = refp[m * 4 + 1];
  const float rw = refp[m * 4 + 2], rh = refp[m * 4 + 3];

  const float* lg = &offaw[(size_t)m * 288 + 192 + h * 12];
  float law[12];
  float mx = -1e30f;
#pragma unroll
  for (int p = 0; p < 12; ++p) { law[p] = lg[p]; mx = fmaxf(mx, law[p]); }
  float ssum = 0.f;
#pragma unroll
  for (int p = 0; p < 12; ++p) { law[p] = __expf(law[p] - mx); ssum += law[p]; }
  const float rinv = 1.f / ssum;

  const float* ob = &offaw[(size_t)m * 288 + h * 24];
  float outv = 0.f;
#pragma unroll
  for (int p = 0; p < 12; ++p) {
    const int lvl = p >> 2;
    const int W = (lvl == 0) ? 80 : ((lvl == 1) ? 40 : 20);
    const int HWsz = W * W;
    const float* img;
    if (lvl == 0)      img = v0 + (size_t)bn * (80 * 80 * 32);
    else if (lvl == 1) img = v1 + (size_t)bn * (40 * 40 * 32);
    else               img = v2 + (size_t)bn * (20 * 20 * 32);

    float ox = ob[2 * p], oy = ob[2 * p + 1];
    float px = (rx + ox * 0.125f * rw) * (float)W - 0.5f;
    float py = (ry + oy * 0.125f * rh) * (float)W - 0.5f;
    float x0f = floorf(px), y0f = floorf(py);
    float fx = px - x0f, fy = py - y0f;
    int x0 = (int)x0f, y0 = (int)y0f;
    float sv = 0.f;
#pragma unroll
    for (int t = 0; t < 4; ++t) {
      int xi = x0 + (t & 1), yi = y0 + (t >> 1);
      float wgt = ((t & 1) ? fx : (1.f - fx)) * ((t >> 1) ? fy : (1.f - fy));
      if (xi >= 0 && xi < W && yi >= 0 && yi < W) {
        float val = HWC ? img[(size_t)(yi * W + xi) * 32 + c]
                        : img[(size_t)c * HWsz + yi * W + xi];
        sv += wgt * val;
      }
    }
    outv += law[p] * rinv * sv;
  }
  catbuf[(size_t)m * 512 + 256 + h * 32 + c] = outv;
}

// ---------------------------------------------------------------------------
// Elementwise add (float4 granularity)
// ---------------------------------------------------------------------------
__global__ void add_kernel(const float* __restrict__ a,
                           const float* __restrict__ b, float* __restrict__ o,
                           int n4) {
  int i = blockIdx.x * blockDim.x + threadIdx.x;
  if (i < n4) {
    float4 x = ((const float4*)a)[i];
    float4 y = ((const float4*)b)[i];
    float4 z; z.x = x.x + y.x; z.y = x.y + y.y; z.z = x.z + y.z; z.w = x.w + y.w;
    ((float4*)o)[i] = z;
  }
}

// ---------------------------------------------------------------------------
// Column-concat two row-major matrices (also used for biases with Krows=1)
// ---------------------------------------------------------------------------
__global__ void concat_cols_kernel(const float* __restrict__ A,
                                   const float* __restrict__ B,
                                   float* __restrict__ o, int N1, int N2) {
  int k = blockIdx.x;
  int NT = N1 + N2;
  for (int n = threadIdx.x; n < NT; n += blockDim.x)
    o[(size_t)k * NT + n] =
        (n < N1) ? A[(size_t)k * N1 + n] : B[(size_t)k * N2 + (n - N1)];
}

// ---------------------------------------------------------------------------
// LayerNorm kernels: one wave (64 lanes) per 256-wide row, 4 rows/block.
// ---------------------------------------------------------------------------
__device__ inline void wave_reduce2(float& s, float& sq) {
#pragma unroll
  for (int msk = 32; msk >= 1; msk >>= 1) {
    s += __shfl_xor(s, msk, 64);
    sq += __shfl_xor(sq, msk, 64);
  }
}

// t1 = LN(target + wo_out); writes t1 into cat[:, :256] and qd = t1 + qpos
__global__ __launch_bounds__(256)
void ln_residual_kernel(const float* __restrict__ target,
                        const float* __restrict__ qpos,
                        const float* __restrict__ wo,
                        const float* __restrict__ gamma,
                        const float* __restrict__ beta,
                        float* __restrict__ catbuf, float* __restrict__ qd) {
  const int tid = threadIdx.x;
  const int lane = tid & 63, wid = tid >> 6;
  const int row = blockIdx.x * 4 + wid;
  const size_t base = (size_t)row * 256 + lane * 4;
  float4 t = *(const float4*)&target[base];
  float4 w = *(const float4*)&wo[base];
  float x0 = t.x + w.x, x1 = t.y + w.y, x2 = t.z + w.z, x3 = t.w + w.w;
  float s = x0 + x1 + x2 + x3;
  float sq = x0 * x0 + x1 * x1 + x2 * x2 + x3 * x3;
  wave_reduce2(s, sq);
  float mean = s * (1.f / 256.f);
  float var = sq * (1.f / 256.f) - mean * mean;
  float inv = 1.f / sqrtf(var + 1e-5f);
  int cb = lane * 4;
  float4 g = *(const float4*)&gamma[cb];
  float4 be = *(const float4*)&beta[cb];
  float4 y;
  y.x = (x0 - mean) * inv * g.x + be.x;
  y.y = (x1 - mean) * inv * g.y + be.y;
  y.z = (x2 - mean) * inv * g.z + be.z;
  y.w = (x3 - mean) * inv * g.w + be.w;
  *(float4*)&catbuf[(size_t)row * 512 + cb] = y;
  float4 qp = *(const float4*)&qpos[base];
  float4 z; z.x = y.x + qp.x; z.y = y.y + qp.y; z.z = y.z + qp.z; z.w = y.w + qp.w;
  *(float4*)&qd[base] = z;
}

// t3 = LN(g1*t1 + g2*t2d)
__global__ __launch_bounds__(256)
void ln_gate_kernel(const float* __restrict__ gbuf,
                    const float* __restrict__ catbuf,
                    const float* __restrict__ gamma,
                    const float* __restrict__ beta, float* __restrict__ t3) {
  const int tid = threadIdx.x;
  const int lane = tid & 63, wid = tid >> 6;
  const int row = blockIdx.x * 4 + wid;
  const int cb = lane * 4;
  float4 g1 = *(const float4*)&gbuf[(size_t)row * 512 + cb];
  float4 g2 = *(const float4*)&gbuf[(size_t)row * 512 + 256 + cb];
  float4 t1 = *(const float4*)&catbuf[(size_t)row * 512 + cb];
  float4 t2 = *(const float4*)&catbuf[(size_t)row * 512 + 256 + cb];
  float x0 = g1.x * t1.x + g2.x * t2.x;
  float x1 = g1.y * t1.y + g2.y * t2.y;
  float x2 = g1.z * t1.z + g2.z * t2.z;
  float x3 = g1.w * t1.w + g2.w * t2.w;
  float s = x0 + x1 + x2 + x3;
  float sq = x0 * x0 + x1 * x1 + x2 * x2 + x3 * x3;
  wave_reduce2(s, sq);
  float mean = s * (1.f / 256.f);
  float var = sq * (1.f / 256.f) - mean * mean;
  float inv = 1.f / sqrtf(var + 1e-5f);
  float4 g = *(const float4*)&gamma[cb];
  float4 be = *(const float4*)&beta[cb];
  float4 y;
  y.x = (x0 - mean) * inv * g.x + be.x;
  y.y = (x1 - mean) * inv * g.y + be.y;
  y.z = (x2 - mean) * inv * g.z + be.z;
  y.w = (x3 - mean) * inv * g.w + be.w;
  *(float4*)&t3[(size_t)row * 256 + cb] = y;
}

// out = LN(clip(t3 + ffo))
__global__ __launch_bounds__(256)
void ln_final_kernel(const float* __restrict__ t3, const float* __restrict__ ffo,
                     const float* __restrict__ gamma,
                     const float* __restrict__ beta, float* __restrict__ out) {
  const int tid = threadIdx.x;
  const int lane = tid & 63, wid = tid >> 6;
  const int row = blockIdx.x * 4 + wid;
  const size_t base = (size_t)row * 256 + lane * 4;
  float4 a = *(const float4*)&t3[base];
  float4 b = *(const float4*)&ffo[base];
  float x0 = fminf(fmaxf(a.x + b.x, -65504.f), 65504.f);
  float x1 = fminf(fmaxf(a.y + b.y, -65504.f), 65504.f);
  float x2 = fminf(fmaxf(a.z + b.z, -65504.f), 65504.f);
  float x3 = fminf(fmaxf(a.w + b.w, -65504.f), 65504.f);
  float s = x0 + x1 + x2 + x3;
  float sq = x0 * x0 + x1 * x1 + x2 * x2 + x3 * x3;
  wave_reduce2(s, sq);
  float mean = s * (1.f / 256.f);
  float var = sq * (1.f / 256.f) - mean * mean;
  float inv = 1.f / sqrtf(var + 1e-5f);
  int cb = lane * 4;
  float4 g = *(const float4*)&gamma[cb];
  float4 be = *(const float4*)&beta[cb];
  float4 y;
  y.x = (x0 - mean) * inv * g.x + be.x;
  y.y = (x1 - mean) * inv * g.y + be.y;
  y.z = (x2 - mean) * inv * g.z + be.z;
  y.w = (x3 - mean) * inv * g.w + be.w;
  *(float4*)&out[base] = y;
}

// ---------------------------------------------------------------------------
// Launch
// ---------------------------------------------------------------------------
extern "C" void kernel_launch(void* const* d_in, const int* in_sizes, int n_in,
                              void* d_out, int out_size, void* d_ws,
                              size_t ws_size, hipStream_t stream) {
  const float* target = (const float*)d_in[0];
  const float* qpos   = (const float*)d_in[1];
  const float* refp   = (const float*)d_in[2];
  const float* value0 = (const float*)d_in[3];
  const float* value1 = (const float*)d_in[4];
  const float* value2 = (const float*)d_in[5];
  const float* Wq = (const float*)d_in[6];
  const float* bq = (const float*)d_in[7];
  const float* Wk = (const float*)d_in[8];
  const float* bk = (const float*)d_in[9];
  const float* Wv = (const float*)d_in[10];
  const float* bv = (const float*)d_in[11];
  const float* Wo = (const float*)d_in[12];
  const float* bo = (const float*)d_in[13];
  const float* ln1_g = (const float*)d_in[14];
  const float* ln1_b = (const float*)d_in[15];
  const float* W_off = (const float*)d_in[16];
  const float* b_off = (const float*)d_in[17];
  const float* W_aw  = (const float*)d_in[18];
  const float* b_aw  = (const float*)d_in[19];
  const float* Wg = (const float*)d_in[20];
  const float* bg = (const float*)d_in[21];
  const float* lng_g = (const float*)d_in[22];
  const float* lng_b = (const float*)d_in[23];
  const float* W1 = (const float*)d_in[24];
  const float* b1 = (const float*)d_in[25];
  const float* W2 = (const float*)d_in[26];
  const float* b2 = (const float*)d_in[27];
  const float* ln3_g = (const float*)d_in[28];
  const float* ln3_b = (const float*)d_in[29];

  float* ws = (float*)d_ws;
  // workspace layout (element offsets)
  const size_t P1  = 0;                 // 16,384,000: qk -> offaw -> ffh
  const size_t P2  = 16384000;          //  8,192,000: qkproj -> g
  const size_t P3  = 24576000;          //  4,096,000: v -> wo_out -> ffo
  const size_t P4  = 28672000;          //  4,096,000: sa -> qd -> t3
  const size_t CAT = 32768000;          //  8,192,000: [t1 | t2d]
  const size_t P5  = 40960000;          //  ~206k: concat'd weights
  const size_t VT0 = 41216000;          // 52,428,800
  const size_t VT1 = VT0 + 52428800;    // 13,107,200
  const size_t VT2 = VT1 + 13107200;    //  3,276,800
  const size_t END_FULL = VT2 + 3276800;

  const bool fast = ws_size >= END_FULL * sizeof(float);

  float* qk_buf  = ws + P1;   // reused: offaw, ffh
  float* qkproj  = ws + P2;   // reused: g
  float* vbuf    = ws + P3;   // reused: wo_out, ffo
  float* sa_buf  = ws + P4;   // reused: qd, t3
  float* catb    = ws + CAT;
  float* wqk = ws + P5;
  float* bqk = wqk + 131072;
  float* woa = bqk + 512;
  float* boa = woa + 73728;

  // concat weights [Wq|Wk], [b_off... etc]
  concat_cols_kernel<<<256, 256, 0, stream>>>(Wq, Wk, wqk, 256, 256);
  concat_cols_kernel<<<1, 256, 0, stream>>>(bq, bk, bqk, 256, 256);
  concat_cols_kernel<<<256, 256, 0, stream>>>(W_off, W_aw, woa, 192, 96);
  concat_cols_kernel<<<1, 256, 0, stream>>>(b_off, b_aw, boa, 192, 96);

  // transpose values to HWC (fast path)
  if (fast) {
    transpose_kernel<<<dim3(256, 100), 256, 0, stream>>>(value0, ws + VT0, 6400);
    transpose_kernel<<<dim3(256, 25), 256, 0, stream>>>(value1, ws + VT1, 1600);
    transpose_kernel<<<dim3(256, 7), 256, 0, stream>>>(value2, ws + VT2, 400);
  }

  // qk = target + query_pos
  add_kernel<<<4000, 256, 0, stream>>>(target, qpos, qk_buf, 1024000);

  // q|k projection and v projection
  gemm_kernel<false, false><<<dim3(4, 125), 256, 0, stream>>>(
      qk_buf, wqk, bqk, qkproj, MTOT, 512, 256);
  gemm_kernel<false, false><<<dim3(2, 125), 256, 0, stream>>>(
      target, Wv, bv, vbuf, MTOT, 256, 256);

  // self-attention
  attn_kernel<<<dim3(256, 2), 256, 0, stream>>>(qkproj, vbuf, sa_buf);

  // Wo projection (sa -> wo_out in P3)
  gemm_kernel<false, false><<<dim3(2, 125), 256, 0, stream>>>(
      sa_buf, Wo, bo, vbuf, MTOT, 256, 256);

  // t1 = LN(target + wo_out) -> cat[:, :256]; qd = t1 + qpos -> P4
  ln_residual_kernel<<<4000, 256, 0, stream>>>(target, qpos, vbuf, ln1_g, ln1_b,
                                               catb, sa_buf);

  // offsets + attention-weights projection (qd -> offaw in P1)
  gemm_kernel<false, false><<<dim3(3, 125), 256, 0, stream>>>(
      sa_buf, woa, boa, qk_buf, MTOT, 288, 256);

  // deformable sampling -> cat[:, 256:]
  if (fast) {
    sampler_kernel<true><<<16000, 256, 0, stream>>>(
        qk_buf, refp, ws + VT0, ws + VT1, ws + VT2, catb);
  } else {
    sampler_kernel<false><<<16000, 256, 0, stream>>>(
        qk_buf, refp, value0, value1, value2, catb);
  }

  // gate: g = sigmoid(cat @ Wg + bg) -> P2
  gemm_kernel<false, true><<<dim3(4, 125), 256, 0, stream>>>(
      catb, Wg, bg, qkproj, MTOT, 512, 512);

  // t3 = LN(g1*t1 + g2*t2d) -> P4
  ln_gate_kernel<<<4000, 256, 0, stream>>>(qkproj, catb, lng_g, lng_b, sa_buf);

  // FFN
  gemm_kernel<true, false><<<dim3(8, 125), 256, 0, stream>>>(
      sa_buf, W1, b1, qk_buf, MTOT, FF, 256);
  gemm_kernel<false, false><<<dim3(2, 125), 256, 0, stream>>>(
      qk_buf, W2, b2, vbuf, MTOT, 256, FF);

  // out = LN(clip(t3 + ffo))
  ln_final_kernel<<<4000, 256, 0, stream>>>(sa_buf, vbuf, ln3_g, ln3_b,
                                            (float*)d_out);
}

// Round 4
// 1081.924 us; speedup vs baseline: 1.4027x; 1.4027x over previous
//
#include <hip/hip_runtime.h>
#include <hip/hip_bf16.h>
#include <hip/hip_fp16.h>
#include <math.h>

// ---------------------------------------------------------------------------
// Problem constants
// ---------------------------------------------------------------------------
#define BS   32
#define LQ   500
#define DIM  256
#define NHD  8
#define HD   32
#define FF   1024
#define SP   12
#define MTOT (BS*LQ)          // 16000 rows

typedef __bf16 bf16_t;
typedef __bf16 bf16x8 __attribute__((ext_vector_type(8)));
typedef __bf16 bf16x4 __attribute__((ext_vector_type(4)));
typedef float  f32x4  __attribute__((ext_vector_type(4)));

__device__ inline void split2(float x, bf16_t& h, bf16_t& l) {
  h = (bf16_t)x;
  l = (bf16_t)(x - (float)h);
}

// ===========================================================================
// bf16x2-split MFMA GEMM:  C = act(A @ B + bias)
// A as hi/lo bf16 [M][K]; B as B^T hi/lo bf16 [N][K].
// C = Ah@Bh + Ah@Bl + Al@Bh  (fp32 MFMA accum; ~2^-16 rel error)
// BM=128, BN=128, BK=32, 256 threads = 4 waves (2x2 of 64x64).
// LDS double-buffered: 2 x 4 tiles of [128][40] bf16 = 80 KiB
// (80 B row stride -> conflict-free ds_read_b128).
// M%128==0, K%32==0; N%128==0 (288 padded to 384, pad cols never read).
// ===========================================================================
#define MFMA16(a, b, c) __builtin_amdgcn_mfma_f32_16x16x32_bf16(a, b, c, 0, 0, 0)

template<bool RELU, bool SIG, bool SPLIT_OUT>
__global__ __launch_bounds__(256)
void mfma_gemm(const bf16_t* __restrict__ Ah, const bf16_t* __restrict__ Al,
               const bf16_t* __restrict__ BTh, const bf16_t* __restrict__ BTl,
               const float* __restrict__ bias, float* __restrict__ C,
               bf16_t* __restrict__ Ch, bf16_t* __restrict__ Cl,
               int N, int K) {
  __shared__ __align__(16) bf16_t sm[2][4][128 * 40];
  const int tid = threadIdx.x;
  const int m0 = blockIdx.y * 128;
  const int n0 = blockIdx.x * 128;
  const int lane = tid & 63;
  const int wid = tid >> 6;
  const int wr = (wid >> 1) * 64;   // wave row offset in tile
  const int wc = (wid & 1) * 64;    // wave col offset in tile
  const int r16 = lane & 15;
  const int kg = lane >> 4;         // 0..3 (k-group of 8)

  // staging: thread t loads rows (t>>2) and (t>>2)+64, 16B chunk (t&3)
  const int srow = tid >> 2;
  const int sc = tid & 3;
  const size_t a0 = (size_t)(m0 + srow) * K + sc * 8;
  const size_t a1 = (size_t)(m0 + srow + 64) * K + sc * 8;
  const size_t b0 = (size_t)(n0 + srow) * K + sc * 8;
  const size_t b1 = (size_t)(n0 + srow + 64) * K + sc * 8;
  const int w0 = srow * 40 + sc * 8;
  const int w1 = (srow + 64) * 40 + sc * 8;

  f32x4 acc[4][4];
#pragma unroll
  for (int i = 0; i < 4; ++i)
#pragma unroll
    for (int j = 0; j < 4; ++j) {
      acc[i][j][0] = 0.f; acc[i][j][1] = 0.f;
      acc[i][j][2] = 0.f; acc[i][j][3] = 0.f;
    }

  uint4 rg0, rg1, rg2, rg3, rg4, rg5, rg6, rg7;
#define LOAD_TILE(ko)                                   \
  do {                                                  \
    rg0 = *(const uint4*)(Ah + a0 + (ko));              \
    rg1 = *(const uint4*)(Ah + a1 + (ko));              \
    rg2 = *(const uint4*)(Al + a0 + (ko));              \
    rg3 = *(const uint4*)(Al + a1 + (ko));              \
    rg4 = *(const uint4*)(BTh + b0 + (ko));             \
    rg5 = *(const uint4*)(BTh + b1 + (ko));             \
    rg6 = *(const uint4*)(BTl + b0 + (ko));             \
    rg7 = *(const uint4*)(BTl + b1 + (ko));             \
  } while (0)
#define STORE_TILE(bf)                                  \
  do {                                                  \
    *(uint4*)&sm[bf][0][w0] = rg0;                      \
    *(uint4*)&sm[bf][0][w1] = rg1;                      \
    *(uint4*)&sm[bf][1][w0] = rg2;                      \
    *(uint4*)&sm[bf][1][w1] = rg3;                      \
    *(uint4*)&sm[bf][2][w0] = rg4;                      \
    *(uint4*)&sm[bf][2][w1] = rg5;                      \
    *(uint4*)&sm[bf][3][w0] = rg6;                      \
    *(uint4*)&sm[bf][3][w1] = rg7;                      \
  } while (0)

  const int nk = K >> 5;
  LOAD_TILE(0);
  STORE_TILE(0);
  __syncthreads();

  for (int kt = 0; kt < nk; ++kt) {
    const int cur = kt & 1;
    if (kt + 1 < nk) LOAD_TILE((size_t)(kt + 1) * 32);  // prefetch (hides HBM)

    const bf16_t* Ash = sm[cur][0];
    const bf16_t* Asl = sm[cur][1];
    const bf16_t* Bsh = sm[cur][2];
    const bf16_t* Bsl = sm[cur][3];
    bf16x8 fah[4], fal[4], fbh[4], fbl[4];
#pragma unroll
    for (int t = 0; t < 4; ++t) {
      const int ao = (wr + t * 16 + r16) * 40 + kg * 8;
      const int bo = (wc + t * 16 + r16) * 40 + kg * 8;
      fah[t] = *(const bf16x8*)&Ash[ao];
      fal[t] = *(const bf16x8*)&Asl[ao];
      fbh[t] = *(const bf16x8*)&Bsh[bo];
      fbl[t] = *(const bf16x8*)&Bsl[bo];
    }
#pragma unroll
    for (int i = 0; i < 4; ++i)
#pragma unroll
      for (int j = 0; j < 4; ++j) {
        acc[i][j] = MFMA16(fah[i], fbh[j], acc[i][j]);
        acc[i][j] = MFMA16(fah[i], fbl[j], acc[i][j]);
        acc[i][j] = MFMA16(fal[i], fbh[j], acc[i][j]);
      }
    if (kt + 1 < nk) STORE_TILE(cur ^ 1);
    __syncthreads();
  }

  // epilogue: D lane mapping col=lane&15, row=(lane>>4)*4+e   [m89-verified]
#pragma unroll
  for (int j = 0; j < 4; ++j) {
    const int col = n0 + wc + j * 16 + r16;
    const float bj = bias[col];
#pragma unroll
    for (int i = 0; i < 4; ++i) {
      const int rbase = m0 + wr + i * 16 + kg * 4;
#pragma unroll
      for (int e = 0; e < 4; ++e) {
        float v = acc[i][j][e] + bj;
        if (RELU) v = fmaxf(v, 0.f);
        if (SIG) v = 1.f / (1.f + __expf(-v));
        const size_t off = (size_t)(rbase + e) * N + col;
        if constexpr (SPLIT_OUT) {
          bf16_t h, l;
          split2(v, h, l);
          Ch[off] = h;
          Cl[off] = l;
        } else {
          C[off] = v;
        }
      }
    }
  }
#undef LOAD_TILE
#undef STORE_TILE
}

// ===========================================================================
// Conversion kernels
// ===========================================================================
// W [K][N] fp32 -> B^T hi/lo bf16 [N][K]
__global__ void convT_kernel(const float* __restrict__ src,
                             bf16_t* __restrict__ dh, bf16_t* __restrict__ dl,
                             int K, int N) {
  int idx = blockIdx.x * 256 + threadIdx.x;
  if (idx < N * K) {
    int n = idx / K, k = idx - n * K;
    float x = src[(size_t)k * N + n];
    bf16_t h, l;
    split2(x, h, l);
    dh[idx] = h;
    dl[idx] = l;
  }
}

// fp32 -> hi/lo bf16 (4 elements / thread)
__global__ void conv_act_kernel(const float* __restrict__ src,
                                bf16_t* __restrict__ dh,
                                bf16_t* __restrict__ dl, int n4) {
  int i = blockIdx.x * blockDim.x + threadIdx.x;
  if (i < n4) {
    float4 x = ((const float4*)src)[i];
    bf16x4 h4, l4;
    bf16_t h, l;
    split2(x.x, h, l); h4[0] = h; l4[0] = l;
    split2(x.y, h, l); h4[1] = h; l4[1] = l;
    split2(x.z, h, l); h4[2] = h; l4[2] = l;
    split2(x.w, h, l); h4[3] = h; l4[3] = l;
    *(bf16x4*)&dh[(size_t)i * 4] = h4;
    *(bf16x4*)&dl[(size_t)i * 4] = l4;
  }
}

// (a+b) -> hi/lo bf16
__global__ void add_conv_kernel(const float* __restrict__ a,
                                const float* __restrict__ b,
                                bf16_t* __restrict__ dh,
                                bf16_t* __restrict__ dl, int n4) {
  int i = blockIdx.x * blockDim.x + threadIdx.x;
  if (i < n4) {
    float4 x = ((const float4*)a)[i];
    float4 y = ((const float4*)b)[i];
    bf16x4 h4, l4;
    bf16_t h, l;
    split2(x.x + y.x, h, l); h4[0] = h; l4[0] = l;
    split2(x.y + y.y, h, l); h4[1] = h; l4[1] = l;
    split2(x.z + y.z, h, l); h4[2] = h; l4[2] = l;
    split2(x.w + y.w, h, l); h4[3] = h; l4[3] = l;
    *(bf16x4*)&dh[(size_t)i * 4] = h4;
    *(bf16x4*)&dl[(size_t)i * 4] = l4;
  }
}

// bias concat with zero pad
__global__ void bias_cat_kernel(const float* __restrict__ a, int na,
                                const float* __restrict__ b, int nb,
                                float* __restrict__ o, int nt) {
  int i = threadIdx.x + blockIdx.x * blockDim.x;
  if (i < nt) o[i] = i < na ? a[i] : (i < na + nb ? b[i - na] : 0.f);
}

// ===========================================================================
// Legacy fp32 tiled GEMM (fallback path only)
// ===========================================================================
template<bool RELU, bool SIG>
__global__ __launch_bounds__(256)
void gemm_kernel(const float* __restrict__ A, const float* __restrict__ W,
                 const float* __restrict__ bias, float* __restrict__ C,
                 int M, int N, int K) {
  __shared__ __align__(16) float As[16][132];
  __shared__ __align__(16) float Bs[16][132];
  const int tid = threadIdx.x;
  const int tx = tid & 15, ty = tid >> 4;
  const int m0 = blockIdx.y * 128;
  const int n0 = blockIdx.x * 128;

  float acc[8][8];
#pragma unroll
  for (int i = 0; i < 8; ++i)
#pragma unroll
    for (int j = 0; j < 8; ++j) acc[i][j] = 0.f;

  const int nk = K >> 4;
  for (int kt = 0; kt < nk; ++kt) {
    const int k0 = kt << 4;
#pragma unroll
    for (int l = 0; l < 2; ++l) {
      int idx = tid + l * 256;
      int row = idx >> 2;
      int kk4 = (idx & 3) << 2;
      float4 av = *reinterpret_cast<const float4*>(
          &A[(size_t)(m0 + row) * K + k0 + kk4]);
      As[kk4 + 0][row] = av.x;
      As[kk4 + 1][row] = av.y;
      As[kk4 + 2][row] = av.z;
      As[kk4 + 3][row] = av.w;
    }
#pragma unroll
    for (int l = 0; l < 2; ++l) {
      int idx = tid + l * 256;
      int kk = idx >> 5;
      int n4 = (idx & 31) << 2;
      int col = n0 + n4;
      float4 bv = make_float4(0.f, 0.f, 0.f, 0.f);
      if (col < N)
        bv = *reinterpret_cast<const float4*>(&W[(size_t)(k0 + kk) * N + col]);
      *reinterpret_cast<float4*>(&Bs[kk][n4]) = bv;
    }
    __syncthreads();
#pragma unroll
    for (int kk = 0; kk < 16; ++kk) {
      float a[8], b[8];
      *(float4*)&a[0] = *(const float4*)&As[kk][ty * 8 + 0];
      *(float4*)&a[4] = *(const float4*)&As[kk][ty * 8 + 4];
      *(float4*)&b[0] = *(const float4*)&Bs[kk][tx * 8 + 0];
      *(float4*)&b[4] = *(const float4*)&Bs[kk][tx * 8 + 4];
#pragma unroll
      for (int i = 0; i < 8; ++i)
#pragma unroll
        for (int j = 0; j < 8; ++j) acc[i][j] += a[i] * b[j];
    }
    __syncthreads();
  }
  float bb[8];
#pragma unroll
  for (int j = 0; j < 8; ++j) {
    int col = n0 + tx * 8 + j;
    bb[j] = (col < N) ? bias[col] : 0.f;
  }
#pragma unroll
  for (int i = 0; i < 8; ++i) {
    int mrow = m0 + ty * 8 + i;
#pragma unroll
    for (int j4 = 0; j4 < 2; ++j4) {
      int col = n0 + tx * 8 + j4 * 4;
      if (col < N) {
        float4 o;
        float v0 = acc[i][j4 * 4 + 0] + bb[j4 * 4 + 0];
        float v1 = acc[i][j4 * 4 + 1] + bb[j4 * 4 + 1];
        float v2 = acc[i][j4 * 4 + 2] + bb[j4 * 4 + 2];
        float v3 = acc[i][j4 * 4 + 3] + bb[j4 * 4 + 3];
        if (RELU) {
          v0 = fmaxf(v0, 0.f); v1 = fmaxf(v1, 0.f);
          v2 = fmaxf(v2, 0.f); v3 = fmaxf(v3, 0.f);
        }
        if (SIG) {
          v0 = 1.f / (1.f + __expf(-v0));
          v1 = 1.f / (1.f + __expf(-v1));
          v2 = 1.f / (1.f + __expf(-v2));
          v3 = 1.f / (1.f + __expf(-v3));
        }
        o.x = v0; o.y = v1; o.z = v2; o.w = v3;
        *reinterpret_cast<float4*>(&C[(size_t)mrow * N + col]) = o;
      }
    }
  }
}

// ===========================================================================
// Flash self-attention, 10-row chunked inner loop for ILP.
// grid (256 bh, 2 q-tiles), block 256 (250 active).
// ===========================================================================
template<bool SPLIT>
__global__ __launch_bounds__(256)
void attn_kernel(const float* __restrict__ qkproj, const float* __restrict__ v,
                 float* __restrict__ sa32, bf16_t* __restrict__ sah,
                 bf16_t* __restrict__ sal) {
  __shared__ __align__(16) float Ks[250 * 32];
  __shared__ __align__(16) float Vs[250 * 32];
  const int tid = threadIdx.x;
  const int bh = blockIdx.x;
  const int b = bh >> 3, h = bh & 7;
  const int qi = blockIdx.y * 250 + tid;
  const bool active = tid < 250;

  float q[32], acc[32];
  float mrun = -1e30f, l = 0.f;
  if (active) {
    const float* qp = &qkproj[(size_t)(b * 500 + qi) * 512 + h * 32];
#pragma unroll
    for (int d4 = 0; d4 < 8; ++d4)
      *(float4*)&q[d4 * 4] = *(const float4*)&qp[d4 * 4];
#pragma unroll
    for (int d = 0; d < 32; ++d) {
      q[d] *= 0.17677669529663687f;   // pre-scale by 1/sqrt(32)
      acc[d] = 0.f;
    }
  }

  for (int t0 = 0; t0 < 500; t0 += 250) {
    __syncthreads();
    for (int idx = tid; idx < 2000; idx += 256) {
      int r = idx >> 3, d4 = idx & 7;
      size_t row = (size_t)(b * 500 + t0 + r);
      ((float4*)Ks)[idx] =
          *(const float4*)&qkproj[row * 512 + 256 + h * 32 + d4 * 4];
      ((float4*)Vs)[idx] = *(const float4*)&v[row * 256 + h * 32 + d4 * 4];
    }
    __syncthreads();
    if (active) {
      for (int r0 = 0; r0 < 250; r0 += 10) {
        float s[10];
#pragma unroll
        for (int i = 0; i < 10; ++i) {
          const float4* kr = (const float4*)&Ks[(r0 + i) * 32];
          float s0 = 0.f, s1 = 0.f, s2 = 0.f, s3 = 0.f;
#pragma unroll
          for (int d4 = 0; d4 < 8; ++d4) {
            float4 kv = kr[d4];
            s0 += q[d4 * 4 + 0] * kv.x;
            s1 += q[d4 * 4 + 1] * kv.y;
            s2 += q[d4 * 4 + 2] * kv.z;
            s3 += q[d4 * 4 + 3] * kv.w;
          }
          s[i] = (s0 + s1) + (s2 + s3);
        }
        float cmx = s[0];
#pragma unroll
        for (int i = 1; i < 10; ++i) cmx = fmaxf(cmx, s[i]);
        if (cmx > mrun) {
          float corr = __expf(mrun - cmx);
          l *= corr;
#pragma unroll
          for (int d = 0; d < 32; ++d) acc[d] *= corr;
          mrun = cmx;
        }
        float p[10];
#pragma unroll
        for (int i = 0; i < 10; ++i) {
          p[i] = __expf(s[i] - mrun);
          l += p[i];
        }
#pragma unroll
        for (int i = 0; i < 10; ++i) {
          const float4* vr = (const float4*)&Vs[(r0 + i) * 32];
#pragma unroll
          for (int d4 = 0; d4 < 8; ++d4) {
            float4 vv = vr[d4];
            acc[d4 * 4 + 0] += p[i] * vv.x;
            acc[d4 * 4 + 1] += p[i] * vv.y;
            acc[d4 * 4 + 2] += p[i] * vv.z;
            acc[d4 * 4 + 3] += p[i] * vv.w;
          }
        }
      }
    }
  }
  if (active) {
    float inv = 1.f / l;
    const size_t base = (size_t)(b * 500 + qi) * 256 + h * 32;
    if constexpr (SPLIT) {
#pragma unroll
      for (int d4 = 0; d4 < 4; ++d4) {
        bf16x8 hv, lv;
#pragma unroll
        for (int jj = 0; jj < 8; ++jj) {
          bf16_t hh, ll;
          split2(acc[d4 * 8 + jj] * inv, hh, ll);
          hv[jj] = hh;
          lv[jj] = ll;
        }
        *(bf16x8*)&sah[base + d4 * 8] = hv;
        *(bf16x8*)&sal[base + d4 * 8] = lv;
      }
    } else {
#pragma unroll
      for (int d4 = 0; d4 < 8; ++d4) {
        float4 o;
        o.x = acc[d4 * 4 + 0] * inv;
        o.y = acc[d4 * 4 + 1] * inv;
        o.z = acc[d4 * 4 + 2] * inv;
        o.w = acc[d4 * 4 + 3] * inv;
        *(float4*)&sa32[base + d4 * 4] = o;
      }
    }
  }
}

// ===========================================================================
// CHW fp32 -> HWC fp16 transpose of one value level
// ===========================================================================
__global__ __launch_bounds__(256)
void transpose_kernel(const float* __restrict__ in, __half* __restrict__ out,
                      int HW) {
  __shared__ float ts[32][65];
  const int bn = blockIdx.x;
  const int p0 = blockIdx.y * 64;
  const int tid = threadIdx.x;
  {
    const int lane = tid & 63, cg = tid >> 6;
#pragma unroll
    for (int i = 0; i < 8; ++i) {
      int cc = cg * 8 + i;
      int p = p0 + lane;
      if (p < HW) ts[cc][lane] = in[(size_t)bn * 32 * HW + (size_t)cc * HW + p];
    }
  }
  __syncthreads();
  {
    const int cc = tid & 31, pg = tid >> 5;
#pragma unroll
    for (int i = 0; i < 8; ++i) {
      int p = pg * 8 + i;
      int pos = p0 + p;
      if (pos < HW)
        out[(size_t)bn * HW * 32 + (size_t)pos * 32 + cc] =
            __float2half(ts[cc][p]);
    }
  }
}

// ===========================================================================
// Deformable sampler. grid 16000, block 256 = 8 heads x 32 ch.
// offaw stride `os` (288 fallback / 384 mfma path).
// ===========================================================================
template<bool HWC, bool SPLIT, typename VT>
__global__ __launch_bounds__(256)
void sampler_kernel(const float* __restrict__ offaw,
                    const float* __restrict__ refp,
                    const VT* __restrict__ v0,
                    const VT* __restrict__ v1,
                    const VT* __restrict__ v2,
                    float* __restrict__ catbuf, bf16_t* __restrict__ cath,
                    bf16_t* __restrict__ catl, int os) {
  const int m = blockIdx.x;
  const int tid = threadIdx.x;
  const int h = tid >> 5, c = tid & 31;
  const int b = m / 500;
  const int bn = b * 8 + h;

  const float rx = refp[m * 4 + 0], ry = refp[m * 4 + 1];
  const float rw = refp[m * 4 + 2], rh = refp[m * 4 + 3];

  const float* lg = &offaw[(size_t)m * os + 192 + h * 12];
  float law[12];
  float mx = -1e30f;
#pragma unroll
  for (int p = 0; p < 12; ++p) { law[p] = lg[p]; mx = fmaxf(mx, law[p]); }
  float ssum = 0.f;
#pragma unroll
  for (int p = 0; p < 12; ++p) { law[p] = __expf(law[p] - mx); ssum += law[p]; }
  const float rinv = 1.f / ssum;

  const float* ob = &offaw[(size_t)m * os + h * 24];
  float outv = 0.f;
#pragma unroll
  for (int p = 0; p < 12; ++p) {
    const int lvl = p >> 2;
    const int W = (lvl == 0) ? 80 : ((lvl == 1) ? 40 : 20);
    const int HWsz = W * W;
    const VT* img;
    if (lvl == 0)      img = v0 + (size_t)bn * (80 * 80 * 32);
    else if (lvl == 1) img = v1 + (size_t)bn * (40 * 40 * 32);
    else               img = v2 + (size_t)bn * (20 * 20 * 32);

    float ox = ob[2 * p], oy = ob[2 * p + 1];
    float px = (rx + ox * 0.125f * rw) * (float)W - 0.5f;
    float py = (ry + oy * 0.125f * rh) * (float)W - 0.5f;
    float x0f = floorf(px), y0f = floorf(py);
    float fx = px - x0f, fy = py - y0f;
    int x0 = (int)x0f, y0 = (int)y0f;
    float sv = 0.f;
#pragma unroll
    for (int t = 0; t < 4; ++t) {
      int xi = x0 + (t & 1), yi = y0 + (t >> 1);
      float wgt = ((t & 1) ? fx : (1.f - fx)) * ((t >> 1) ? fy : (1.f - fy));
      if (xi >= 0 && xi < W && yi >= 0 && yi < W) {
        float val = HWC ? (float)img[(size_t)(yi * W + xi) * 32 + c]
                        : (float)img[(size_t)c * HWsz + yi * W + xi];
        sv += wgt * val;
      }
    }
    outv += law[p] * rinv * sv;
  }
  const size_t off = (size_t)m * 512 + 256 + h * 32 + c;
  catbuf[off] = outv;
  if constexpr (SPLIT) {
    bf16_t hh, ll;
    split2(outv, hh, ll);
    cath[off] = hh;
    catl[off] = ll;
  }
}

// ===========================================================================
// Elementwise add / concat (fallback)
// ===========================================================================
__global__ void add_kernel(const float* __restrict__ a,
                           const float* __restrict__ b, float* __restrict__ o,
                           int n4) {
  int i = blockIdx.x * blockDim.x + threadIdx.x;
  if (i < n4) {
    float4 x = ((const float4*)a)[i];
    float4 y = ((const float4*)b)[i];
    float4 z; z.x = x.x + y.x; z.y = x.y + y.y; z.z = x.z + y.z; z.w = x.w + y.w;
    ((float4*)o)[i] = z;
  }
}

__global__ void concat_cols_kernel(const float* __restrict__ A,
                                   const float* __restrict__ B,
                                   float* __restrict__ o, int N1, int N2) {
  int k = blockIdx.x;
  int NT = N1 + N2;
  for (int n = threadIdx.x; n < NT; n += blockDim.x)
    o[(size_t)k * NT + n] =
        (n < N1) ? A[(size_t)k * N1 + n] : B[(size_t)k * N2 + (n - N1)];
}

// ===========================================================================
// LayerNorm kernels (one wave per 256-wide row, 4 rows/block)
// ===========================================================================
__device__ inline void wave_reduce2(float& s, float& sq) {
#pragma unroll
  for (int msk = 32; msk >= 1; msk >>= 1) {
    s += __shfl_xor(s, msk, 64);
    sq += __shfl_xor(sq, msk, 64);
  }
}

// t1 = LN(target + wo_out); t1 -> cat[:, :256] (+ hi/lo); qd = t1 + qpos
template<bool SPLIT>
__global__ __launch_bounds__(256)
void ln_residual_kernel(const float* __restrict__ target,
                        const float* __restrict__ qpos,
                        const float* __restrict__ wo,
                        const float* __restrict__ gamma,
                        const float* __restrict__ beta,
                        float* __restrict__ catbuf, float* __restrict__ qd32,
                        bf16_t* __restrict__ cath, bf16_t* __restrict__ catl,
                        bf16_t* __restrict__ qdh, bf16_t* __restrict__ qdl) {
  const int tid = threadIdx.x;
  const int lane = tid & 63, wid = tid >> 6;
  const int row = blockIdx.x * 4 + wid;
  const size_t base = (size_t)row * 256 + lane * 4;
  float4 t = *(const float4*)&target[base];
  float4 w = *(const float4*)&wo[base];
  float x0 = t.x + w.x, x1 = t.y + w.y, x2 = t.z + w.z, x3 = t.w + w.w;
  float s = x0 + x1 + x2 + x3;
  float sq = x0 * x0 + x1 * x1 + x2 * x2 + x3 * x3;
  wave_reduce2(s, sq);
  float mean = s * (1.f / 256.f);
  float var = sq * (1.f / 256.f) - mean * mean;
  float inv = 1.f / sqrtf(var + 1e-5f);
  int cb = lane * 4;
  float4 g = *(const float4*)&gamma[cb];
  float4 be = *(const float4*)&beta[cb];
  float4 y;
  y.x = (x0 - mean) * inv * g.x + be.x;
  y.y = (x1 - mean) * inv * g.y + be.y;
  y.z = (x2 - mean) * inv * g.z + be.z;
  y.w = (x3 - mean) * inv * g.w + be.w;
  *(float4*)&catbuf[(size_t)row * 512 + cb] = y;
  float4 qp = *(const float4*)&qpos[base];
  float z0 = y.x + qp.x, z1 = y.y + qp.y, z2 = y.z + qp.z, z3 = y.w + qp.w;
  if constexpr (SPLIT) {
    bf16x4 h4, l4;
    bf16_t hh, ll;
    split2(y.x, hh, ll); h4[0] = hh; l4[0] = ll;
    split2(y.y, hh, ll); h4[1] = hh; l4[1] = ll;
    split2(y.z, hh, ll); h4[2] = hh; l4[2] = ll;
    split2(y.w, hh, ll); h4[3] = hh; l4[3] = ll;
    *(bf16x4*)&cath[(size_t)row * 512 + cb] = h4;
    *(bf16x4*)&catl[(size_t)row * 512 + cb] = l4;
    split2(z0, hh, ll); h4[0] = hh; l4[0] = ll;
    split2(z1, hh, ll); h4[1] = hh; l4[1] = ll;
    split2(z2, hh, ll); h4[2] = hh; l4[2] = ll;
    split2(z3, hh, ll); h4[3] = hh; l4[3] = ll;
    *(bf16x4*)&qdh[base] = h4;
    *(bf16x4*)&qdl[base] = l4;
  } else {
    float4 z; z.x = z0; z.y = z1; z.z = z2; z.w = z3;
    *(float4*)&qd32[base] = z;
  }
}

// t3 = LN(g1*t1 + g2*t2d)  (+ hi/lo)
template<bool SPLIT>
__global__ __launch_bounds__(256)
void ln_gate_kernel(const float* __restrict__ gbuf,
                    const float* __restrict__ catbuf,
                    const float* __restrict__ gamma,
                    const float* __restrict__ beta, float* __restrict__ t3,
                    bf16_t* __restrict__ t3h, bf16_t* __restrict__ t3l) {
  const int tid = threadIdx.x;
  const int lane = tid & 63, wid = tid >> 6;
  const int row = blockIdx.x * 4 + wid;
  const int cb = lane * 4;
  float4 g1 = *(const float4*)&gbuf[(size_t)row * 512 + cb];
  float4 g2 = *(const float4*)&gbuf[(size_t)row * 512 + 256 + cb];
  float4 t1 = *(const float4*)&catbuf[(size_t)row * 512 + cb];
  float4 t2 = *(const float4*)&catbuf[(size_t)row * 512 + 256 + cb];
  float x0 = g1.x * t1.x + g2.x * t2.x;
  float x1 = g1.y * t1.y + g2.y * t2.y;
  float x2 = g1.z * t1.z + g2.z * t2.z;
  float x3 = g1.w * t1.w + g2.w * t2.w;
  float s = x0 + x1 + x2 + x3;
  float sq = x0 * x0 + x1 * x1 + x2 * x2 + x3 * x3;
  wave_reduce2(s, sq);
  float mean = s * (1.f / 256.f);
  float var = sq * (1.f / 256.f) - mean * mean;
  float inv = 1.f / sqrtf(var + 1e-5f);
  float4 g = *(const float4*)&gamma[cb];
  float4 be = *(const float4*)&beta[cb];
  float4 y;
  y.x = (x0 - mean) * inv * g.x + be.x;
  y.y = (x1 - mean) * inv * g.y + be.y;
  y.z = (x2 - mean) * inv * g.z + be.z;
  y.w = (x3 - mean) * inv * g.w + be.w;
  *(float4*)&t3[(size_t)row * 256 + cb] = y;
  if constexpr (SPLIT) {
    bf16x4 h4, l4;
    bf16_t hh, ll;
    split2(y.x, hh, ll); h4[0] = hh; l4[0] = ll;
    split2(y.y, hh, ll); h4[1] = hh; l4[1] = ll;
    split2(y.z, hh, ll); h4[2] = hh; l4[2] = ll;
    split2(y.w, hh, ll); h4[3] = hh; l4[3] = ll;
    *(bf16x4*)&t3h[(size_t)row * 256 + cb] = h4;
    *(bf16x4*)&t3l[(size_t)row * 256 + cb] = l4;
  }
}

// out = LN(clip(t3 + ffo))
__global__ __launch_bounds__(256)
void ln_final_kernel(const float* __restrict__ t3, const float* __restrict__ ffo,
                     const float* __restrict__ gamma,
                     const float* __restrict__ beta, float* __restrict__ out) {
  const int tid = threadIdx.x;
  const int lane = tid & 63, wid = tid >> 6;
  const int row = blockIdx.x * 4 + wid;
  const size_t base = (size_t)row * 256 + lane * 4;
  float4 a = *(const float4*)&t3[base];
  float4 b = *(const float4*)&ffo[base];
  float x0 = fminf(fmaxf(a.x + b.x, -65504.f), 65504.f);
  float x1 = fminf(fmaxf(a.y + b.y, -65504.f), 65504.f);
  float x2 = fminf(fmaxf(a.z + b.z, -65504.f), 65504.f);
  float x3 = fminf(fmaxf(a.w + b.w, -65504.f), 65504.f);
  float s = x0 + x1 + x2 + x3;
  float sq = x0 * x0 + x1 * x1 + x2 * x2 + x3 * x3;
  wave_reduce2(s, sq);
  float mean = s * (1.f / 256.f);
  float var = sq * (1.f / 256.f) - mean * mean;
  float inv = 1.f / sqrtf(var + 1e-5f);
  int cb = lane * 4;
  float4 g = *(const float4*)&gamma[cb];
  float4 be = *(const float4*)&beta[cb];
  float4 y;
  y.x = (x0 - mean) * inv * g.x + be.x;
  y.y = (x1 - mean) * inv * g.y + be.y;
  y.z = (x2 - mean) * inv * g.z + be.z;
  y.w = (x3 - mean) * inv * g.w + be.w;
  *(float4*)&out[base] = y;
}

// ===========================================================================
// Launch
// ===========================================================================
extern "C" void kernel_launch(void* const* d_in, const int* in_sizes, int n_in,
                              void* d_out, int out_size, void* d_ws,
                              size_t ws_size, hipStream_t stream) {
  const float* target = (const float*)d_in[0];
  const float* qpos   = (const float*)d_in[1];
  const float* refp   = (const float*)d_in[2];
  const float* value0 = (const float*)d_in[3];
  const float* value1 = (const float*)d_in[4];
  const float* value2 = (const float*)d_in[5];
  const float* Wq = (const float*)d_in[6];
  const float* bq = (const float*)d_in[7];
  const float* Wk = (const float*)d_in[8];
  const float* bk = (const float*)d_in[9];
  const float* Wv = (const float*)d_in[10];
  const float* bv = (const float*)d_in[11];
  const float* Wo = (const float*)d_in[12];
  const float* bo = (const float*)d_in[13];
  const float* ln1_g = (const float*)d_in[14];
  const float* ln1_b = (const float*)d_in[15];
  const float* W_off = (const float*)d_in[16];
  const float* b_off = (const float*)d_in[17];
  const float* W_aw  = (const float*)d_in[18];
  const float* b_aw  = (const float*)d_in[19];
  const float* Wg = (const float*)d_in[20];
  const float* bg = (const float*)d_in[21];
  const float* lng_g = (const float*)d_in[22];
  const float* lng_b = (const float*)d_in[23];
  const float* W1 = (const float*)d_in[24];
  const float* b1 = (const float*)d_in[25];
  const float* W2 = (const float*)d_in[26];
  const float* b2 = (const float*)d_in[27];
  const float* ln3_g = (const float*)d_in[28];
  const float* ln3_b = (const float*)d_in[29];

  char* wsb = (char*)d_ws;

  // ------------ MFMA-path workspace layout (byte offsets, all 16B-aligned) --
  // VT fp16 region (reused later for FFN hidden hi/lo bf16)
  const size_t oVT0 = 0;                        // 104,857,600 B (fp16 HWC v0)
  const size_t oVT1 = oVT0 + 104857600;         //  26,214,400 B
  const size_t oVT2 = oVT1 + 26214400;          //   6,553,600 B
  const size_t oB1  = oVT2 + 6553600;           // qkproj/g fp32 (offaw alias) 32,768,000 B
  const size_t oB2  = oB1 + 32768000;           // vbuf fp32 16,384,000 B
  const size_t oB3  = oB2 + 16384000;           // catb fp32 32,768,000 B
  const size_t oB4  = oB3 + 32768000;           // t3 fp32 16,384,000 B
  const size_t oB5  = oB4 + 16384000;           // qk/qd hi+lo bf16 65,536,000 B
  const size_t oB6  = oB5 + 65536000;           // tgt/cat hi+lo bf16 32,768,000 B
  const size_t oB7  = oB6 + 32768000;           // sa/t3 hi+lo bf16 16,384,000 B
  const size_t oB8  = oB7 + 16384000;           // weights hi+lo bf16 4,587,520 B
  const size_t oB9  = oB8 + 4587520;            // biases fp32
  const size_t NEED_MFMA = oB9 + 4096;          // ~355.2 MB

  const bool use_mfma = ws_size >= NEED_MFMA;

  if (use_mfma) {
    __half* vt0 = (__half*)(wsb + oVT0);
    __half* vt1 = (__half*)(wsb + oVT1);
    __half* vt2 = (__half*)(wsb + oVT2);
    float* qkproj = (float*)(wsb + oB1);   // then offaw, then g
    float* vbuf   = (float*)(wsb + oB2);   // v -> wo_out -> ffo
    float* catb   = (float*)(wsb + oB3);
    float* t3b    = (float*)(wsb + oB4);
    bf16_t* qdH  = (bf16_t*)(wsb + oB5);
    bf16_t* qdL  = qdH + 16384000;
    bf16_t* catH = (bf16_t*)(wsb + oB6);
    bf16_t* catL = catH + 8192000;
    bf16_t* saH  = (bf16_t*)(wsb + oB7);
    bf16_t* saL  = saH + 4096000;
    bf16_t* WH   = (bf16_t*)(wsb + oB8);
    bf16_t* WL   = WH + 1146880;
    float* bqk = (float*)(wsb + oB9);      // 512
    float* boa = bqk + 512;                // 384
    // FFN hidden aliases the (dead-by-then) VT region
    bf16_t* ffH = (bf16_t*)(wsb + oVT0);
    bf16_t* ffL = (bf16_t*)(wsb + oVT0 + 32768000);

    // weight B^T element offsets within WH/WL
    const size_t oWqk = 0, oWv = 131072, oWo = 196608, oWoa = 262144,
                 oWg = 360448, oW1 = 622592, oW2 = 884736;

    // -- weight conversion + transpose (hi/lo) --
    convT_kernel<<<256, 256, 0, stream>>>(Wq, WH + oWqk, WL + oWqk, 256, 256);
    convT_kernel<<<256, 256, 0, stream>>>(Wk, WH + oWqk + 65536,
                                          WL + oWqk + 65536, 256, 256);
    convT_kernel<<<256, 256, 0, stream>>>(Wv, WH + oWv, WL + oWv, 256, 256);
    convT_kernel<<<256, 256, 0, stream>>>(Wo, WH + oWo, WL + oWo, 256, 256);
    convT_kernel<<<192, 256, 0, stream>>>(W_off, WH + oWoa, WL + oWoa, 256, 192);
    convT_kernel<<<96, 256, 0, stream>>>(W_aw, WH + oWoa + 192 * 256,
                                         WL + oWoa + 192 * 256, 256, 96);
    convT_kernel<<<1024, 256, 0, stream>>>(Wg, WH + oWg, WL + oWg, 512, 512);
    convT_kernel<<<1024, 256, 0, stream>>>(W1, WH + oW1, WL + oW1, 256, 1024);
    convT_kernel<<<1024, 256, 0, stream>>>(W2, WH + oW2, WL + oW2, 1024, 256);
    bias_cat_kernel<<<2, 256, 0, stream>>>(bq, 256, bk, 256, bqk, 512);
    bias_cat_kernel<<<2, 256, 0, stream>>>(b_off, 192, b_aw, 96, boa, 384);

    // -- HWC fp16 transposes for sampler --
    transpose_kernel<<<dim3(256, 100), 256, 0, stream>>>(value0, vt0, 6400);
    transpose_kernel<<<dim3(256, 25), 256, 0, stream>>>(value1, vt1, 1600);
    transpose_kernel<<<dim3(256, 7), 256, 0, stream>>>(value2, vt2, 400);

    // -- activations: qk = target + qpos -> B5; tgt -> B6 --
    add_conv_kernel<<<4000, 256, 0, stream>>>(target, qpos, qdH, qdL, 1024000);
    conv_act_kernel<<<4000, 256, 0, stream>>>(target, catH, catL, 1024000);

    // -- q|k proj and v proj --
    mfma_gemm<false, false, false><<<dim3(4, 125), 256, 0, stream>>>(
        qdH, qdL, WH + oWqk, WL + oWqk, bqk, qkproj, nullptr, nullptr, 512, 256);
    mfma_gemm<false, false, false><<<dim3(2, 125), 256, 0, stream>>>(
        catH, catL, WH + oWv, WL + oWv, bv, vbuf, nullptr, nullptr, 256, 256);

    // -- self-attention (writes sa hi/lo) --
    attn_kernel<true><<<dim3(256, 2), 256, 0, stream>>>(qkproj, vbuf, nullptr,
                                                        saH, saL);

    // -- Wo projection -> vbuf (wo_out) --
    mfma_gemm<false, false, false><<<dim3(2, 125), 256, 0, stream>>>(
        saH, saL, WH + oWo, WL + oWo, bo, vbuf, nullptr, nullptr, 256, 256);

    // -- t1 = LN(target + wo_out); cat fp32+hi/lo, qd hi/lo --
    ln_residual_kernel<true><<<4000, 256, 0, stream>>>(
        target, qpos, vbuf, ln1_g, ln1_b, catb, nullptr, catH, catL, qdH, qdL);

    // -- offsets/attn-weights projection (N padded to 384) -> B1 --
    mfma_gemm<false, false, false><<<dim3(3, 125), 256, 0, stream>>>(
        qdH, qdL, WH + oWoa, WL + oWoa, boa, qkproj, nullptr, nullptr, 384, 256);

    // -- deformable sampling (fp16 HWC) -> cat[:,256:] fp32+hi/lo --
    sampler_kernel<true, true, __half><<<16000, 256, 0, stream>>>(
        qkproj, refp, vt0, vt1, vt2, catb, catH, catL, 384);

    // -- gate: g = sigmoid(cat @ Wg + bg) -> B1 --
    mfma_gemm<false, true, false><<<dim3(4, 125), 256, 0, stream>>>(
        catH, catL, WH + oWg, WL + oWg, bg, qkproj, nullptr, nullptr, 512, 512);

    // -- t3 = LN(g1*t1 + g2*t2d) -> B4 fp32 + B7 hi/lo --
    ln_gate_kernel<true><<<4000, 256, 0, stream>>>(qkproj, catb, lng_g, lng_b,
                                                   t3b, saH, saL);

    // -- FFN --
    mfma_gemm<true, false, true><<<dim3(8, 125), 256, 0, stream>>>(
        saH, saL, WH + oW1, WL + oW1, b1, nullptr, ffH, ffL, 1024, 256);
    mfma_gemm<false, false, false><<<dim3(2, 125), 256, 0, stream>>>(
        ffH, ffL, WH + oW2, WL + oW2, b2, vbuf, nullptr, nullptr, 256, 1024);

    // -- out = LN(clip(t3 + ffo)) --
    ln_final_kernel<<<4000, 256, 0, stream>>>(t3b, vbuf, ln3_g, ln3_b,
                                              (float*)d_out);
    return;
  }

  // ------------------- fallback: R1 fp32 path (CHW sampler) -----------------
  float* ws = (float*)d_ws;
  const size_t P1 = 0;                 // qk -> offaw -> ffh
  const size_t P2 = 16384000;          // qkproj -> g
  const size_t P3 = 24576000;          // v -> wo_out -> ffo
  const size_t P4 = 28672000;          // sa -> qd -> t3
  const size_t CAT = 32768000;         // [t1 | t2d]
  const size_t P5 = 40960000;          // concat'd weights

  float* qk_buf = ws + P1;
  float* qkproj = ws + P2;
  float* vbuf   = ws + P3;
  float* sa_buf = ws + P4;
  float* catb   = ws + CAT;
  float* wqk = ws + P5;
  float* bqk2 = wqk + 131072;
  float* woa = bqk2 + 512;
  float* boa2 = woa + 73728;

  concat_cols_kernel<<<256, 256, 0, stream>>>(Wq, Wk, wqk, 256, 256);
  concat_cols_kernel<<<1, 256, 0, stream>>>(bq, bk, bqk2, 256, 256);
  concat_cols_kernel<<<256, 256, 0, stream>>>(W_off, W_aw, woa, 192, 96);
  concat_cols_kernel<<<1, 256, 0, stream>>>(b_off, b_aw, boa2, 192, 96);

  add_kernel<<<4000, 256, 0, stream>>>(target, qpos, qk_buf, 1024000);
  gemm_kernel<false, false><<<dim3(4, 125), 256, 0, stream>>>(
      qk_buf, wqk, bqk2, qkproj, MTOT, 512, 256);
  gemm_kernel<false, false><<<dim3(2, 125), 256, 0, stream>>>(
      target, Wv, bv, vbuf, MTOT, 256, 256);
  attn_kernel<false><<<dim3(256, 2), 256, 0, stream>>>(qkproj, vbuf, sa_buf,
                                                       nullptr, nullptr);
  gemm_kernel<false, false><<<dim3(2, 125), 256, 0, stream>>>(
      sa_buf, Wo, bo, vbuf, MTOT, 256, 256);
  ln_residual_kernel<false><<<4000, 256, 0, stream>>>(
      target, qpos, vbuf, ln1_g, ln1_b, catb, sa_buf, nullptr, nullptr, nullptr,
      nullptr);
  gemm_kernel<false, false><<<dim3(3, 125), 256, 0, stream>>>(
      sa_buf, woa, boa2, qk_buf, MTOT, 288, 256);
  sampler_kernel<false, false, float><<<16000, 256, 0, stream>>>(
      qk_buf, refp, value0, value1, value2, catb, nullptr, nullptr, 288);
  gemm_kernel<false, true><<<dim3(4, 125), 256, 0, stream>>>(
      catb, Wg, bg, qkproj, MTOT, 512, 512);
  ln_gate_kernel<false><<<4000, 256, 0, stream>>>(qkproj, catb, lng_g, lng_b,
                                                  sa_buf, nullptr, nullptr);
  gemm_kernel<true, false><<<dim3(8, 125), 256, 0, stream>>>(
      sa_buf, W1, b1, qk_buf, MTOT, FF, 256);
  gemm_kernel<false, false><<<dim3(2, 125), 256, 0, stream>>>(
      qk_buf, W2, b2, vbuf, MTOT, 256, FF);
  ln_final_kernel<<<4000, 256, 0, stream>>>(sa_buf, vbuf, ln3_g, ln3_b,
                                            (float*)d_out);
}